// Round 6
// baseline (726.504 us; speedup 1.0000x reference)
//
#include <hip/hip_runtime.h>
#include <stdint.h>

typedef short bf16x8 __attribute__((ext_vector_type(8)));
typedef float f32x4 __attribute__((ext_vector_type(4)));

#define BM 256
#define BN 256
#define BK 64
#define ABUF_U 16384   // 256*64 ushorts (32KB) A region
#define BUF_U  32768   // A+B per buffer in ushorts (64KB); 2 buffers = 128KB

#define AS1 __attribute__((address_space(1)))
#define AS3 __attribute__((address_space(3)))

__device__ __forceinline__ ushort f2bf(float x) {
    uint32_t u = __float_as_uint(x);
    u += 0x7FFFu + ((u >> 16) & 1u);
    return (ushort)(u >> 16);
}

__device__ __forceinline__ void gload16(const void* g, void* l) {
    __builtin_amdgcn_global_load_lds((const AS1 void*)g, (AS3 void*)l, 16, 0, 0);
}

// issue 2 staging loads (chunks i0, i0+1 of 8) for K-offset kt into buffer buf
#define ISSUE2(kt, buf, i0)                                                          \
    do {                                                                             \
        gload16(((i0) < 4 ? Ap : Bp) + goff[i0] + (kt), smem + (buf)*BUF_U + loff[i0]); \
        gload16((((i0)+1) < 4 ? Ap : Bp) + goff[(i0)+1] + (kt), smem + (buf)*BUF_U + loff[(i0)+1]); \
    } while (0)

// C[M,N] = A[M,K] * B[N,K]^T, bf16 MFMA 16x16x32.
// 256x256 tile, 512 threads (8 waves: 2M x 4N, per-wave 128x64, acc[8][4]).
// K-loop: 8-phase-style schedule (T3+T4+T5), double-buffered LDS, counted vmcnt.
// Epilogues: LDS-staged wide stores — fragments scattered into a swizzled LDS
// image, read back as linear 16B chunks, stored as full-line dwordx4.
// MODE 0: bf16 out = acc (+bias), optional transposed copy (per-batch [col][row])
// MODE 1: scores: e=exp(tanh(acc)); write E + E^T bf16; atomic rowsum/colsum
// MODE 2: bf16 out = acc / scale[row]
// MODE 3: f32 out = acc + bias[col] + resid[row,col]
template<int MODE, bool HAS_BIAS, bool WRITE_T>
__global__ __launch_bounds__(512, 2)
void gemm_bt(const ushort* __restrict__ Aptr_, const ushort* __restrict__ Bptr_,
             void* __restrict__ Cptr_, ushort* __restrict__ CTptr_,
             const float* __restrict__ bias, const float* __restrict__ resid_,
             float* __restrict__ rsum_, float* __restrict__ csum_,
             const float* __restrict__ scale_,
             int M, int N, int K, int lda, int ldb, int ldc,
             long sA, long sB, long sC, long sCT, long sSum,
             int ldct, int rbshift)
{
    extern __shared__ ushort smem[];   // 2 * BUF_U ushorts (128KB)

    const int z    = blockIdx.z;
    const int m0   = blockIdx.x * BM;
    const int n0   = blockIdx.y * BN;
    const int tid  = threadIdx.x;
    const int lane = tid & 63;
    const int wave = tid >> 6;
    const int wr   = wave >> 2;        // 0..1 -> rows wr*128..+128
    const int wcn  = wave & 3;         // 0..3 -> cols wcn*64..+64
    const int g    = lane >> 4, c = lane & 15;

    const ushort* Ap = Aptr_ + z * sA;
    const ushort* Bp = Bptr_ + z * sB;

    // staging: linear LDS dest (wave-uniform base + lane*16), XOR-swizzled
    // global source chunk; ds_read applies the same XOR -> conflict-free.
    long goff[8]; int loff[8];
    #pragma unroll
    for (int u = 0; u < 4; ++u) {
        const int li  = u * 512 + tid;       // chunk 0..2047 (A and B each)
        const int row = li >> 3;             // 0..255
        const int gck = (li & 7) ^ (row & 7);
        goff[u]     = (long)(m0 + row) * lda + gck * 8;
        loff[u]     = li * 8;
        goff[u + 4] = (long)(n0 + row) * ldb + gck * 8;
        loff[u + 4] = ABUF_U + li * 8;
    }

    f32x4 acc[8][4] = {};

    const int nk = K / BK;
    // prologue: stage tile 0 into buf 0 (8 loads/thread)
    ISSUE2(0, 0, 0); ISSUE2(0, 0, 2); ISSUE2(0, 0, 4); ISSUE2(0, 0, 6);

    for (int t = 0; t < nk; ++t) {
        const int cur = t & 1, nxt = cur ^ 1;
        const ushort* As = smem + cur * BUF_U;
        const ushort* Bs = As + ABUF_U;
        const bool pf = (t + 1 < nk);
        const int kt1 = (t + 1) * BK;

        if (pf) {
            ISSUE2(kt1, nxt, 0);
            asm volatile("s_waitcnt vmcnt(2)" ::: "memory");  // tile t landed; 2 prefetch in flight
        } else {
            asm volatile("s_waitcnt vmcnt(0)" ::: "memory");  // tail drain
        }
        __builtin_amdgcn_s_barrier();

        bf16x8 af[8], bfr2[2];

        auto ldA = [&](int kk) {
            #pragma unroll
            for (int mi = 0; mi < 8; ++mi) {
                const int row = wr * 128 + mi * 16 + c;
                const int ckq = (kk * 4 + g) ^ (row & 7);
                af[mi] = *(const bf16x8*)&As[row * BK + ckq * 8];
            }
        };
        auto ldB = [&](int kk, int nh) {
            #pragma unroll
            for (int u = 0; u < 2; ++u) {
                const int row = wcn * 64 + (nh * 2 + u) * 16 + c;
                const int ckq = (kk * 4 + g) ^ (row & 7);
                bfr2[u] = *(const bf16x8*)&Bs[row * BK + ckq * 8];
            }
        };
        auto mm = [&](int nh) {
            __builtin_amdgcn_s_setprio(1);
            #pragma unroll
            for (int mi = 0; mi < 8; ++mi)
                #pragma unroll
                for (int u = 0; u < 2; ++u)
                    acc[mi][nh * 2 + u] = __builtin_amdgcn_mfma_f32_16x16x32_bf16(
                        af[mi], bfr2[u], acc[mi][nh * 2 + u], 0, 0, 0);
            __builtin_amdgcn_s_setprio(0);
        };

        // phase 0: A kk0 + B kk0,nh0
        ldA(0); ldB(0, 0);
        if (pf) ISSUE2(kt1, nxt, 2);
        __builtin_amdgcn_s_barrier();
        asm volatile("s_waitcnt lgkmcnt(0)" ::: "memory");
        __builtin_amdgcn_sched_barrier(0);
        mm(0);
        __builtin_amdgcn_s_barrier();
        // phase 1: B kk0,nh1 (A-frags reused)
        ldB(0, 1);
        if (pf) ISSUE2(kt1, nxt, 4);
        __builtin_amdgcn_s_barrier();
        asm volatile("s_waitcnt lgkmcnt(0)" ::: "memory");
        __builtin_amdgcn_sched_barrier(0);
        mm(1);
        __builtin_amdgcn_s_barrier();
        // phase 2: A kk1 + B kk1,nh0
        ldA(1); ldB(1, 0);
        if (pf) ISSUE2(kt1, nxt, 6);
        __builtin_amdgcn_s_barrier();
        asm volatile("s_waitcnt lgkmcnt(0)" ::: "memory");
        __builtin_amdgcn_sched_barrier(0);
        mm(0);
        __builtin_amdgcn_s_barrier();
        // phase 3: B kk1,nh1
        ldB(1, 1);
        __builtin_amdgcn_s_barrier();
        asm volatile("s_waitcnt lgkmcnt(0)" ::: "memory");
        __builtin_amdgcn_sched_barrier(0);
        mm(1);
        __builtin_amdgcn_s_barrier();
    }

    // ================= epilogues: LDS-staged wide stores =================
    char* img = (char*)smem;   // 128KB scratch, free after K-loop

    if constexpr (MODE == 3) {
        float* Co = (float*)Cptr_;
        // two half-tiles of 128 rows: f32 image [128][256], row stride 1024B
        #pragma unroll
        for (int h = 0; h < 2; ++h) {
            if (h) __syncthreads();
            if (wr == h) {
                #pragma unroll
                for (int mi = 0; mi < 8; ++mi) {
                    const int lr0 = mi * 16 + g * 4;
                    const int s3  = ((lr0 >> 2) & 7) << 4;
                    #pragma unroll
                    for (int ni = 0; ni < 4; ++ni) {
                        const int lc4 = (wcn * 64 + ni * 16 + c) * 4;
                        #pragma unroll
                        for (int r = 0; r < 4; ++r)
                            *(float*)(img + (lr0 + r) * 1024 + (lc4 ^ s3)) = acc[mi][ni][r];
                    }
                }
            }
            __syncthreads();
            #pragma unroll
            for (int cc = 0; cc < 16; ++cc) {
                const int ch = cc * 512 + tid;
                const int rl = ch >> 6;              // 0..127
                const int cb = (ch & 63) * 16;       // byte offset in row
                const int s3 = ((rl >> 2) & 7) << 4;
                float4 v = *(const float4*)(img + rl * 1024 + (cb ^ s3));
                const int col = n0 + (ch & 63) * 4;
                const int row = m0 + h * 128 + rl;
                const float4 bv = *(const float4*)&bias[col];
                const float4 rv = *(const float4*)&resid_[(long)row * ldc + col];
                v.x += bv.x + rv.x; v.y += bv.y + rv.y;
                v.z += bv.z + rv.z; v.w += bv.w + rv.w;
                *(float4*)&Co[(long)row * ldc + col] = v;
            }
        }
        return;
    } else {
        // ---- convert acc -> packed bf16 (+ mode op) ----
        uint us[8][4][2];
        float rowpart[8][4] = {};
        float colpart[4] = {};
        #pragma unroll
        for (int mi = 0; mi < 8; ++mi) {
            float rc[4];
            if constexpr (MODE == 2) {
                const float* sc = scale_ + z * sSum;
                const int row = m0 + wr * 128 + mi * 16 + g * 4;
                #pragma unroll
                for (int r = 0; r < 4; ++r) rc[r] = 1.f / sc[row + r];
            }
            #pragma unroll
            for (int ni = 0; ni < 4; ++ni) {
                ushort v[4];
                #pragma unroll
                for (int r = 0; r < 4; ++r) {
                    float x = acc[mi][ni][r];
                    if constexpr (MODE == 0) {
                        if (HAS_BIAS) x += bias[n0 + wcn * 64 + ni * 16 + c];
                    } else if constexpr (MODE == 1) {
                        const float th = 1.f - 2.f / (__expf(2.f * x) + 1.f);  // tanh
                        x = __expf(th);
                        rowpart[mi][r] += x;
                        colpart[ni]    += x;
                    } else if constexpr (MODE == 2) {
                        x *= rc[r];
                    }
                    v[r] = f2bf(x);
                }
                us[mi][ni][0] = (uint)v[0] | ((uint)v[1] << 16);
                us[mi][ni][1] = (uint)v[2] | ((uint)v[3] << 16);
            }
        }

        // ---- round 1: row-major image -> C/E (bf16, full-line stores) ----
        #pragma unroll
        for (int mi = 0; mi < 8; ++mi) {
            const int lr0 = wr * 128 + mi * 16 + g * 4;
            const int sR  = ((lr0 >> 2) & 7) << 4;
            #pragma unroll
            for (int ni = 0; ni < 4; ++ni) {
                const int lc2 = (wcn * 64 + ni * 16 + c) * 2;
                *(ushort*)(img + (lr0 + 0) * 512 + (lc2 ^ sR)) = (ushort)us[mi][ni][0];
                *(ushort*)(img + (lr0 + 1) * 512 + (lc2 ^ sR)) = (ushort)(us[mi][ni][0] >> 16);
                *(ushort*)(img + (lr0 + 2) * 512 + (lc2 ^ sR)) = (ushort)us[mi][ni][1];
                *(ushort*)(img + (lr0 + 3) * 512 + (lc2 ^ sR)) = (ushort)(us[mi][ni][1] >> 16);
            }
        }
        __syncthreads();
        {
            ushort* Cp = (ushort*)Cptr_ + z * sC;
            #pragma unroll
            for (int cc = 0; cc < 16; ++cc) {
                const int ch = cc * 512 + tid;
                const int r  = ch >> 5;              // 0..255
                const int cb = (ch & 31) * 16;       // byte offset in row
                const int sR = ((r >> 2) & 7) << 4;
                uint4 v = *(const uint4*)(img + r * 512 + (cb ^ sR));
                *(uint4*)((char*)Cp + ((long)(m0 + r) * ldc + n0) * 2 + cb) = v;
            }
        }

        // ---- round 2: transposed image -> CT/ET ----
        if constexpr (MODE == 1 || (MODE == 0 && WRITE_T)) {
            __syncthreads();   // all round-1 reads done before overwrite
            #pragma unroll
            for (int mi = 0; mi < 8; ++mi) {
                const int lr2 = (wr * 128 + mi * 16 + g * 4) * 2;
                #pragma unroll
                for (int ni = 0; ni < 4; ++ni) {
                    const int lc = wcn * 64 + ni * 16 + c;
                    const int sT = (lc & 7) << 4;
                    uint2 w2; w2.x = us[mi][ni][0]; w2.y = us[mi][ni][1];
                    *(uint2*)(img + lc * 512 + (lr2 ^ sT)) = w2;
                }
            }
            __syncthreads();
            #pragma unroll
            for (int cc = 0; cc < 16; ++cc) {
                const int ch = cc * 512 + tid;
                const int cl = ch >> 5;              // 0..255 (output col)
                const int rb = (ch & 31) * 16;       // byte offset in col's row-array
                const int sT = (cl & 7) << 4;
                uint4 v = *(const uint4*)(img + cl * 512 + (rb ^ sT));
                if constexpr (MODE == 1) {
                    *(uint4*)((char*)CTptr_ + (z * sCT + (long)(n0 + cl) * ldct + m0) * 2 + rb) = v;
                } else {
                    const int  bb = m0 >> rbshift;
                    const long ii = m0 & ((1 << rbshift) - 1);
                    *(uint4*)((char*)CTptr_ + ((long)bb * sCT + (long)(n0 + cl) * ldct + ii) * 2 + rb) = v;
                }
            }
        }

        // ---- MODE 1: softmax denominators ----
        if constexpr (MODE == 1) {
            float* rs = rsum_ + z * sSum;
            float* cs = csum_ + z * sSum;
            #pragma unroll
            for (int mi = 0; mi < 8; ++mi) {
                #pragma unroll
                for (int r = 0; r < 4; ++r) {
                    float v = rowpart[mi][r];
                    v += __shfl_xor(v, 1); v += __shfl_xor(v, 2);
                    v += __shfl_xor(v, 4); v += __shfl_xor(v, 8);
                    if (c == 0) atomicAdd(&rs[m0 + wr * 128 + mi * 16 + g * 4 + r], v);
                }
            }
            #pragma unroll
            for (int ni = 0; ni < 4; ++ni) {
                float v = colpart[ni];
                v += __shfl_xor(v, 16); v += __shfl_xor(v, 32);
                if (g == 0) atomicAdd(&cs[n0 + wcn * 64 + ni * 16 + c], v);
            }
        }
    }
}

// f32 -> bf16 elementwise (vectorized 8/thread, grid-stride)
__global__ __launch_bounds__(256)
void cast32to16(const float* __restrict__ in, ushort* __restrict__ out, long n) {
    const long stride = (long)gridDim.x * 256 * 8;
    for (long i = ((long)blockIdx.x * 256 + threadIdx.x) * 8; i < n; i += stride) {
        const float4 f0 = *(const float4*)(in + i);
        const float4 f1 = *(const float4*)(in + i + 4);
        uint4 w;
        w.x = (uint)f2bf(f0.x) | ((uint)f2bf(f0.y) << 16);
        w.y = (uint)f2bf(f0.z) | ((uint)f2bf(f0.w) << 16);
        w.z = (uint)f2bf(f1.x) | ((uint)f2bf(f1.y) << 16);
        w.w = (uint)f2bf(f1.z) | ((uint)f2bf(f1.w) << 16);
        *(uint4*)(out + i) = w;
    }
}

// f32 [R][C] -> bf16 [C][R]
__global__ __launch_bounds__(256)
void tcast(const float* __restrict__ in, ushort* __restrict__ out, int R, int C) {
    __shared__ float t[32][33];
    const int bx = blockIdx.x * 32, by = blockIdx.y * 32;
    const int tx = threadIdx.x, ty = threadIdx.y; // (32, 8)
    for (int i = ty; i < 32; i += 8) {
        const int r = by + i, cc = bx + tx;
        if (r < R && cc < C) t[i][tx] = in[(long)r * C + cc];
    }
    __syncthreads();
    for (int i = ty; i < 32; i += 8) {
        const int cc = bx + i, r = by + tx;
        if (cc < C && r < R) out[(long)cc * R + r] = f2bf(t[tx][i]);
    }
}

// in-place LayerNorm, one row per block
template<int D>
__global__ __launch_bounds__(256)
void ln_rows(float* __restrict__ y, const float* __restrict__ gam, const float* __restrict__ bet) {
    constexpr int NV = D / 256;
    const long row = blockIdx.x;
    float* p = y + row * D;
    const int tid = threadIdx.x;
    float v[NV];
    float s = 0.f, s2 = 0.f;
    #pragma unroll
    for (int k = 0; k < NV; ++k) {
        v[k] = p[tid + k * 256];
        s += v[k]; s2 += v[k] * v[k];
    }
    #pragma unroll
    for (int off = 1; off < 64; off <<= 1) {
        s  += __shfl_xor(s, off);
        s2 += __shfl_xor(s2, off);
    }
    __shared__ float ws[4], ws2[4];
    const int wave = tid >> 6, lane = tid & 63;
    if (lane == 0) { ws[wave] = s; ws2[wave] = s2; }
    __syncthreads();
    s  = ws[0] + ws[1] + ws[2] + ws[3];
    s2 = ws2[0] + ws2[1] + ws2[2] + ws2[3];
    const float mu  = s / D;
    const float var = s2 / D - mu * mu;
    const float rstd = rsqrtf(var + 1e-5f);
    #pragma unroll
    for (int k = 0; k < NV; ++k) {
        const int i = tid + k * 256;
        p[i] = (v[k] - mu) * rstd * gam[i] + bet[i];
    }
}

extern "C" void kernel_launch(void* const* d_in, const int* in_sizes, int n_in,
                              void* d_out, int out_size, void* d_ws, size_t ws_size,
                              hipStream_t stream)
{
    (void)in_sizes; (void)n_in; (void)out_size; (void)ws_size;
    const float* z_a    = (const float*)d_in[0];
    const float* z_b    = (const float*)d_in[1];
    const float* Wa     = (const float*)d_in[2];
    const float* ba     = (const float*)d_in[3];
    const float* Wb     = (const float*)d_in[4];
    const float* bb     = (const float*)d_in[5];
    const float* Wco    = (const float*)d_in[6];
    const float* Woa    = (const float*)d_in[7];
    const float* boa    = (const float*)d_in[8];
    const float* Wob    = (const float*)d_in[9];
    const float* bob    = (const float*)d_in[10];
    const float* ga     = (const float*)d_in[11];
    const float* beta_a = (const float*)d_in[12];
    const float* gb     = (const float*)d_in[13];
    const float* beta_b = (const float*)d_in[14];

    const int Bn = 16, LA = 2048, LB = 2048, DA = 768, DB = 512, DH = 512;
    const long MA = (long)Bn * LA;
    const long MB = (long)Bn * LB;

    char* w = (char*)d_ws;
    size_t off = 0;
    auto alc = [&](size_t bytes) { void* p = w + off; off += (bytes + 255) & ~(size_t)255; return p; };

    ushort* WaT  = (ushort*)alc((size_t)DH * DA * 2);
    ushort* WbT  = (ushort*)alc((size_t)DH * DB * 2);
    ushort* WcoT = (ushort*)alc((size_t)DH * DH * 2);
    ushort* WoaT = (ushort*)alc((size_t)DA * DH * 2);
    ushort* WobT = (ushort*)alc((size_t)DB * DH * 2);
    ushort* h_a  = (ushort*)alc((size_t)MA * DH * 2);
    ushort* h_b  = (ushort*)alc((size_t)MB * DH * 2);
    ushort* h_aT = (ushort*)alc((size_t)Bn * DH * LA * 2);
    ushort* h_bT = (ushort*)alc((size_t)Bn * DH * LB * 2);
    ushort* Ma   = (ushort*)alc((size_t)MA * DH * 2);
    ushort* E    = (ushort*)alc((size_t)Bn * LA * LB * 2);
    ushort* ET   = (ushort*)alc((size_t)Bn * LB * LA * 2);
    ushort* Pa   = (ushort*)alc((size_t)MA * DH * 2);
    ushort* Pb   = (ushort*)alc((size_t)MB * DH * 2);
    float*  rsum = (float*)alc((size_t)Bn * LA * 4);
    float*  csum = (float*)alc((size_t)Bn * LB * 4);

    // bf16 copies of z_a, z_b aliased into E's region (dead before E is written)
    ushort* za16 = E;
    ushort* zb16 = E + (size_t)MA * DA;

    dim3 blk(512, 1, 1);
    dim3 blk256(256, 1, 1);
    dim3 tb(32, 8, 1);
    const int SHM = 2 * BUF_U * 2;   // 131072 B dynamic LDS

    // weight transposes (f32 -> bf16, [K][N] -> [N][K])
    tcast<<<dim3(DH / 32, DA / 32, 1), tb, 0, stream>>>(Wa,  WaT,  DA, DH);
    tcast<<<dim3(DH / 32, DB / 32, 1), tb, 0, stream>>>(Wb,  WbT,  DB, DH);
    tcast<<<dim3(DH / 32, DH / 32, 1), tb, 0, stream>>>(Wco, WcoT, DH, DH);
    tcast<<<dim3(DA / 32, DH / 32, 1), tb, 0, stream>>>(Woa, WoaT, DH, DA);
    tcast<<<dim3(DB / 32, DH / 32, 1), tb, 0, stream>>>(Wob, WobT, DH, DB);

    // activations f32 -> bf16
    cast32to16<<<dim3(2048, 1, 1), blk256, 0, stream>>>(z_a, za16, MA * DA);
    cast32to16<<<dim3(2048, 1, 1), blk256, 0, stream>>>(z_b, zb16, MB * DB);

    // zero softmax denominators (rsum & csum are contiguous)
    hipMemsetAsync(rsum, 0, (size_t)Bn * (LA + LB) * sizeof(float), stream);

    // h_a = z_a @ Wa + ba   (also writes h_aT per batch)
    gemm_bt<0, true, true><<<dim3(MA / BM, DH / BN, 1), blk, SHM, stream>>>(
        za16, WaT, h_a, h_aT, ba, nullptr, nullptr, nullptr, nullptr,
        (int)MA, DH, DA, DA, DA, DH, 0, 0, 0, (long)DH * LA, 0, LA, 11);

    // h_b = z_b @ Wb + bb   (also writes h_bT per batch)
    gemm_bt<0, true, true><<<dim3(MB / BM, DH / BN, 1), blk, SHM, stream>>>(
        zb16, WbT, h_b, h_bT, bb, nullptr, nullptr, nullptr, nullptr,
        (int)MB, DH, DB, DB, DB, DH, 0, 0, 0, (long)DH * LB, 0, LB, 11);

    // Ma = h_a @ W_co
    gemm_bt<0, false, false><<<dim3(MA / BM, DH / BN, 1), blk, SHM, stream>>>(
        h_a, WcoT, Ma, nullptr, nullptr, nullptr, nullptr, nullptr, nullptr,
        (int)MA, DH, DH, DH, DH, DH, 0, 0, 0, 0, 0, 0, 0);

    // scores: E = exp(tanh(Ma @ h_b^T)), E^T, rowsum, colsum  (batched)
    gemm_bt<1, false, false><<<dim3(LA / BM, LB / BN, Bn), blk, SHM, stream>>>(
        Ma, h_b, E, ET, nullptr, nullptr, rsum, csum, nullptr,
        LA, LB, DH, DH, DH, LB,
        (long)LA * DH, (long)LB * DH, (long)LA * LB, (long)LB * LA, LA, LA, 0);

    // Pa = (E @ h_b) / rowsum  (batched)
    gemm_bt<2, false, false><<<dim3(LA / BM, DH / BN, Bn), blk, SHM, stream>>>(
        E, h_bT, Pa, nullptr, nullptr, nullptr, nullptr, nullptr, rsum,
        LA, DH, LB, LB, LB, DH,
        (long)LA * LB, (long)DH * LB, (long)LA * DH, 0, LA, 0, 0);

    // Pb = (E^T @ h_a) / colsum  (batched)
    gemm_bt<2, false, false><<<dim3(LB / BM, DH / BN, Bn), blk, SHM, stream>>>(
        ET, h_aT, Pb, nullptr, nullptr, nullptr, nullptr, nullptr, csum,
        LB, DH, LA, LA, LA, DH,
        (long)LB * LA, (long)DH * LA, (long)LB * DH, 0, LB, 0, 0);

    float* outA = (float*)d_out;
    float* outB = outA + MA * DA;

    // z_a_pre = Pa @ Woa + boa + z_a  -> d_out (f32, in place for LN)
    gemm_bt<3, true, false><<<dim3(MA / BM, DA / BN, 1), blk, SHM, stream>>>(
        Pa, WoaT, outA, nullptr, boa, z_a, nullptr, nullptr, nullptr,
        (int)MA, DA, DH, DH, DH, DA, 0, 0, 0, 0, 0, 0, 0);

    // z_b_pre = Pb @ Wob + bob + z_b  -> d_out
    gemm_bt<3, true, false><<<dim3(MB / BM, DB / BN, 1), blk, SHM, stream>>>(
        Pb, WobT, outB, nullptr, bob, z_b, nullptr, nullptr, nullptr,
        (int)MB, DB, DH, DH, DH, DB, 0, 0, 0, 0, 0, 0, 0);

    // LayerNorms in place on d_out
    ln_rows<768><<<dim3((unsigned)MA, 1, 1), blk256, 0, stream>>>(outA, ga, beta_a);
    ln_rows<512><<<dim3((unsigned)MB, 1, 1), blk256, 0, stream>>>(outB, gb, beta_b);
}

// Round 7
// 713.777 us; speedup vs baseline: 1.0178x; 1.0178x over previous
//
#include <hip/hip_runtime.h>
#include <stdint.h>

typedef short bf16x8 __attribute__((ext_vector_type(8)));
typedef float f32x16 __attribute__((ext_vector_type(16)));

#define BM 256
#define BN 256
#define BK 64
#define ABUF_U 16384   // 256*64 ushorts (32KB) A region
#define BUF_U  32768   // A+B per buffer in ushorts (64KB); 2 buffers = 128KB

#define AS1 __attribute__((address_space(1)))
#define AS3 __attribute__((address_space(3)))

__device__ __forceinline__ ushort f2bf(float x) {
    uint32_t u = __float_as_uint(x);
    u += 0x7FFFu + ((u >> 16) & 1u);
    return (ushort)(u >> 16);
}

__device__ __forceinline__ void gload16(const void* g, void* l) {
    __builtin_amdgcn_global_load_lds((const AS1 void*)g, (AS3 void*)l, 16, 0, 0);
}

// issue 2 staging loads (chunks i0, i0+1 of 8) for K-offset kt into buffer buf
#define ISSUE2(kt, buf, i0)                                                          \
    do {                                                                             \
        gload16(((i0) < 4 ? Ap : Bp) + goff[i0] + (kt), smem + (buf)*BUF_U + loff[i0]); \
        gload16((((i0)+1) < 4 ? Ap : Bp) + goff[(i0)+1] + (kt), smem + (buf)*BUF_U + loff[(i0)+1]); \
    } while (0)

// C[M,N] = A[M,K] * B[N,K]^T, bf16 MFMA **32x32x16**.
// 256x256 tile, 512 threads (8 waves: 2M x 4N, per-wave 128x64 = 4x2 32x32 tiles).
// K-loop: r5's phase schedule (4 phases/tile: 6 ds_read_b128 + 2 gload ->
// barrier -> lgkmcnt(0)+sched_barrier -> setprio(1) 8 MFMA32 setprio(0) -> barrier),
// double-buffered LDS, counted vmcnt(2), both-sides XOR swizzle.
// 32x32 C/D layout (col=lane&31, row=(reg&3)+8*(reg>>2)+4*(lane>>5)) makes every
// row-major store instruction cover full 64B lines -> no partial-line RMW.
// Grid: bijective XCD swizzle (T1/m204) for per-XCD L2 panel reuse.
template<int MODE, bool HAS_BIAS, bool WRITE_T>
__global__ __launch_bounds__(512, 2)
void gemm_bt(const ushort* __restrict__ Aptr_, const ushort* __restrict__ Bptr_,
             void* __restrict__ Cptr_, ushort* __restrict__ CTptr_,
             const float* __restrict__ bias, const float* __restrict__ resid_,
             float* __restrict__ rsum_, float* __restrict__ csum_,
             const float* __restrict__ scale_,
             int M, int N, int K, int lda, int ldb, int ldc,
             long sA, long sB, long sC, long sCT, long sSum,
             int ldct, int rbshift)
{
    extern __shared__ ushort smem[];   // 2 * BUF_U ushorts (128KB)

    // ---- bijective XCD swizzle (T1, m204) ----
    const int gx = gridDim.x, gy = gridDim.y;
    const int nwg = gx * gy * (int)gridDim.z;
    int flat = ((int)blockIdx.z * gy + (int)blockIdx.y) * gx + (int)blockIdx.x;
    {
        const int q8 = nwg >> 3, r8 = nwg & 7;
        const int xcd = flat & 7, loc = flat >> 3;
        flat = (xcd < r8 ? xcd * (q8 + 1) : r8 * (q8 + 1) + (xcd - r8) * q8) + loc;
    }
    const int z   = flat / (gx * gy);
    const int rem = flat - z * (gx * gy);
    const int m0  = (rem % gx) * BM;
    const int n0  = (rem / gx) * BN;

    const int tid  = threadIdx.x;
    const int lane = tid & 63;
    const int wave = tid >> 6;
    const int wr   = wave >> 2;        // 0..1 -> rows wr*128..+128
    const int wcn  = wave & 3;         // 0..3 -> cols wcn*64..+64
    const int lr   = lane & 31, lh = lane >> 5;

    const ushort* Ap = Aptr_ + z * sA;
    const ushort* Bp = Bptr_ + z * sB;

    // staging: linear LDS dest, XOR-swizzled global source chunk (both-sides).
    long goff[8]; int loff[8];
    #pragma unroll
    for (int u = 0; u < 4; ++u) {
        const int li  = u * 512 + tid;       // chunk 0..2047 (A and B each)
        const int row = li >> 3;             // 0..255
        const int gck = (li & 7) ^ (row & 7);
        goff[u]     = (long)(m0 + row) * lda + gck * 8;
        loff[u]     = li * 8;
        goff[u + 4] = (long)(n0 + row) * ldb + gck * 8;
        loff[u + 4] = ABUF_U + li * 8;
    }

    f32x16 acc[4][2] = {};

    const int nk = K / BK;
    // prologue: stage tile 0 into buf 0 (8 loads/thread)
    ISSUE2(0, 0, 0); ISSUE2(0, 0, 2); ISSUE2(0, 0, 4); ISSUE2(0, 0, 6);

    for (int t = 0; t < nk; ++t) {
        const int cur = t & 1, nxt = cur ^ 1;
        const ushort* As = smem + cur * BUF_U;
        const ushort* Bs = As + ABUF_U;
        const bool pf = (t + 1 < nk);
        const int kt1 = (t + 1) * BK;

        if (pf) {
            ISSUE2(kt1, nxt, 0);
            asm volatile("s_waitcnt vmcnt(2)" ::: "memory");  // tile t landed (own loads), then barrier
        } else {
            asm volatile("s_waitcnt vmcnt(0)" ::: "memory");  // tail drain
        }
        __builtin_amdgcn_s_barrier();

        bf16x8 af[4], bfv[2];
        #pragma unroll
        for (int kk = 0; kk < 4; ++kk) {          // 4 k-steps of 16
            #pragma unroll
            for (int tm = 0; tm < 4; ++tm) {
                const int row = wr * 128 + tm * 32 + lr;
                const int ck  = (kk * 2 + lh) ^ (row & 7);
                af[tm] = *(const bf16x8*)&As[row * BK + ck * 8];
            }
            #pragma unroll
            for (int tn = 0; tn < 2; ++tn) {
                const int row = wcn * 64 + tn * 32 + lr;
                const int ck  = (kk * 2 + lh) ^ (row & 7);
                bfv[tn] = *(const bf16x8*)&Bs[row * BK + ck * 8];
            }
            if (pf) {
                if (kk == 0)      ISSUE2(kt1, nxt, 2);
                else if (kk == 1) ISSUE2(kt1, nxt, 4);
                else if (kk == 2) ISSUE2(kt1, nxt, 6);
            }
            __builtin_amdgcn_s_barrier();
            asm volatile("s_waitcnt lgkmcnt(0)" ::: "memory");
            __builtin_amdgcn_sched_barrier(0);
            __builtin_amdgcn_s_setprio(1);
            #pragma unroll
            for (int tm = 0; tm < 4; ++tm)
                #pragma unroll
                for (int tn = 0; tn < 2; ++tn)
                    acc[tm][tn] = __builtin_amdgcn_mfma_f32_32x32x16_bf16(
                        af[tm], bfv[tn], acc[tm][tn], 0, 0, 0);
            __builtin_amdgcn_s_setprio(0);
            __builtin_amdgcn_s_barrier();
        }
    }

    // ---- epilogues (direct stores; 32x32 layout -> full-line coalescing) ----
    const int colb0 = n0 + wcn * 64 + lr;         // tn=0 col
    const int rowbw = m0 + wr * 128 + 4 * lh;     // + tm*32 + (rr&3) + 8*(rr>>2)

    if constexpr (MODE == 3) {
        float* Co = (float*)Cptr_;
        #pragma unroll
        for (int tm = 0; tm < 4; ++tm)
            #pragma unroll
            for (int tn = 0; tn < 2; ++tn) {
                const int col = colb0 + tn * 32;
                const float bv = bias[col];
                #pragma unroll
                for (int q = 0; q < 4; ++q)
                    #pragma unroll
                    for (int s = 0; s < 4; ++s) {
                        const int row = rowbw + tm * 32 + q * 8 + s;
                        const long idx = (long)row * ldc + col;
                        Co[idx] = acc[tm][tn][q * 4 + s] + bv + resid_[idx];
                    }
            }
    } else if constexpr (MODE == 0) {
        ushort* Cp = (ushort*)Cptr_ + z * sC;
        #pragma unroll
        for (int tm = 0; tm < 4; ++tm)
            #pragma unroll
            for (int tn = 0; tn < 2; ++tn) {
                const int col = colb0 + tn * 32;
                const float bv = HAS_BIAS ? bias[col] : 0.f;
                ushort us[16];
                #pragma unroll
                for (int rr = 0; rr < 16; ++rr) us[rr] = f2bf(acc[tm][tn][rr] + bv);
                #pragma unroll
                for (int q = 0; q < 4; ++q)
                    #pragma unroll
                    for (int s = 0; s < 4; ++s)
                        Cp[(long)(rowbw + tm * 32 + q * 8 + s) * ldc + col] = us[q * 4 + s];
                if constexpr (WRITE_T) {
                    #pragma unroll
                    for (int q = 0; q < 4; ++q) {
                        const int gr = rowbw + tm * 32 + q * 8;
                        const int bb = gr >> rbshift;
                        const int ii = gr & ((1 << rbshift) - 1);
                        *(ushort4*)&CTptr_[(long)bb * sCT + (long)col * ldct + ii] =
                            make_ushort4(us[q * 4 + 0], us[q * 4 + 1], us[q * 4 + 2], us[q * 4 + 3]);
                    }
                }
            }
    } else if constexpr (MODE == 1) {
        ushort* Ep  = (ushort*)Cptr_ + z * sC;
        ushort* ETp = CTptr_ + z * sCT;
        float* rs = rsum_ + z * sSum;
        float* cs = csum_ + z * sSum;
        float colp[2] = {0.f, 0.f};
        #pragma unroll
        for (int tm = 0; tm < 4; ++tm) {
            float rowp[16];
            #pragma unroll
            for (int rr = 0; rr < 16; ++rr) rowp[rr] = 0.f;
            #pragma unroll
            for (int tn = 0; tn < 2; ++tn) {
                const int col = colb0 + tn * 32;
                ushort us[16];
                #pragma unroll
                for (int rr = 0; rr < 16; ++rr) {
                    const float x  = acc[tm][tn][rr];
                    const float th = 1.f - 2.f / (__expf(2.f * x) + 1.f);  // tanh(x)
                    const float e  = __expf(th);
                    rowp[rr] += e;
                    colp[tn] += e;
                    us[rr] = f2bf(e);
                }
                #pragma unroll
                for (int q = 0; q < 4; ++q) {
                    #pragma unroll
                    for (int s = 0; s < 4; ++s)
                        Ep[(long)(rowbw + tm * 32 + q * 8 + s) * ldc + col] = us[q * 4 + s];
                    const int gr = rowbw + tm * 32 + q * 8;
                    *(ushort4*)&ETp[(long)col * ldct + gr] =
                        make_ushort4(us[q * 4 + 0], us[q * 4 + 1], us[q * 4 + 2], us[q * 4 + 3]);
                }
            }
            #pragma unroll
            for (int rr = 0; rr < 16; ++rr) {
                float v = rowp[rr];
                v += __shfl_xor(v, 1);  v += __shfl_xor(v, 2);
                v += __shfl_xor(v, 4);  v += __shfl_xor(v, 8);
                v += __shfl_xor(v, 16);
                if (lr == 0)
                    atomicAdd(&rs[rowbw + tm * 32 + (rr & 3) + 8 * (rr >> 2)], v);
            }
        }
        #pragma unroll
        for (int tn = 0; tn < 2; ++tn) {
            float v = colp[tn];
            v += __shfl_xor(v, 32);
            if (lh == 0) atomicAdd(&cs[colb0 + tn * 32], v);
        }
    } else { // MODE == 2
        const float* sc = scale_ + z * sSum;
        ushort* Cp = (ushort*)Cptr_ + z * sC;
        #pragma unroll
        for (int tm = 0; tm < 4; ++tm) {
            float rcp[16];
            #pragma unroll
            for (int rr = 0; rr < 16; ++rr)
                rcp[rr] = 1.f / sc[rowbw + tm * 32 + (rr & 3) + 8 * (rr >> 2)];
            #pragma unroll
            for (int tn = 0; tn < 2; ++tn) {
                const int col = colb0 + tn * 32;
                #pragma unroll
                for (int q = 0; q < 4; ++q)
                    #pragma unroll
                    for (int s = 0; s < 4; ++s)
                        Cp[(long)(rowbw + tm * 32 + q * 8 + s) * ldc + col] =
                            f2bf(acc[tm][tn][q * 4 + s] * rcp[q * 4 + s]);
            }
        }
    }
}

// f32 -> bf16 elementwise (vectorized 8/thread, grid-stride)
__global__ __launch_bounds__(256)
void cast32to16(const float* __restrict__ in, ushort* __restrict__ out, long n) {
    const long stride = (long)gridDim.x * 256 * 8;
    for (long i = ((long)blockIdx.x * 256 + threadIdx.x) * 8; i < n; i += stride) {
        const float4 f0 = *(const float4*)(in + i);
        const float4 f1 = *(const float4*)(in + i + 4);
        uint4 w;
        w.x = (uint)f2bf(f0.x) | ((uint)f2bf(f0.y) << 16);
        w.y = (uint)f2bf(f0.z) | ((uint)f2bf(f0.w) << 16);
        w.z = (uint)f2bf(f1.x) | ((uint)f2bf(f1.y) << 16);
        w.w = (uint)f2bf(f1.z) | ((uint)f2bf(f1.w) << 16);
        *(uint4*)(out + i) = w;
    }
}

// f32 [R][C] -> bf16 [C][R]
__global__ __launch_bounds__(256)
void tcast(const float* __restrict__ in, ushort* __restrict__ out, int R, int C) {
    __shared__ float t[32][33];
    const int bx = blockIdx.x * 32, by = blockIdx.y * 32;
    const int tx = threadIdx.x, ty = threadIdx.y; // (32, 8)
    for (int i = ty; i < 32; i += 8) {
        const int r = by + i, cc = bx + tx;
        if (r < R && cc < C) t[i][tx] = in[(long)r * C + cc];
    }
    __syncthreads();
    for (int i = ty; i < 32; i += 8) {
        const int cc = bx + i, r = by + tx;
        if (cc < C && r < R) out[(long)cc * R + r] = f2bf(t[tx][i]);
    }
}

// in-place LayerNorm, one row per block
template<int D>
__global__ __launch_bounds__(256)
void ln_rows(float* __restrict__ y, const float* __restrict__ gam, const float* __restrict__ bet) {
    constexpr int NV = D / 256;
    const long row = blockIdx.x;
    float* p = y + row * D;
    const int tid = threadIdx.x;
    float v[NV];
    float s = 0.f, s2 = 0.f;
    #pragma unroll
    for (int k = 0; k < NV; ++k) {
        v[k] = p[tid + k * 256];
        s += v[k]; s2 += v[k] * v[k];
    }
    #pragma unroll
    for (int off = 1; off < 64; off <<= 1) {
        s  += __shfl_xor(s, off);
        s2 += __shfl_xor(s2, off);
    }
    __shared__ float ws[4], ws2[4];
    const int wave = tid >> 6, lane = tid & 63;
    if (lane == 0) { ws[wave] = s; ws2[wave] = s2; }
    __syncthreads();
    s  = ws[0] + ws[1] + ws[2] + ws[3];
    s2 = ws2[0] + ws2[1] + ws2[2] + ws2[3];
    const float mu  = s / D;
    const float var = s2 / D - mu * mu;
    const float rstd = rsqrtf(var + 1e-5f);
    #pragma unroll
    for (int k = 0; k < NV; ++k) {
        const int i = tid + k * 256;
        p[i] = (v[k] - mu) * rstd * gam[i] + bet[i];
    }
}

extern "C" void kernel_launch(void* const* d_in, const int* in_sizes, int n_in,
                              void* d_out, int out_size, void* d_ws, size_t ws_size,
                              hipStream_t stream)
{
    (void)in_sizes; (void)n_in; (void)out_size; (void)ws_size;
    const float* z_a    = (const float*)d_in[0];
    const float* z_b    = (const float*)d_in[1];
    const float* Wa     = (const float*)d_in[2];
    const float* ba     = (const float*)d_in[3];
    const float* Wb     = (const float*)d_in[4];
    const float* bb     = (const float*)d_in[5];
    const float* Wco    = (const float*)d_in[6];
    const float* Woa    = (const float*)d_in[7];
    const float* boa    = (const float*)d_in[8];
    const float* Wob    = (const float*)d_in[9];
    const float* bob    = (const float*)d_in[10];
    const float* ga     = (const float*)d_in[11];
    const float* beta_a = (const float*)d_in[12];
    const float* gb     = (const float*)d_in[13];
    const float* beta_b = (const float*)d_in[14];

    const int Bn = 16, LA = 2048, LB = 2048, DA = 768, DB = 512, DH = 512;
    const long MA = (long)Bn * LA;
    const long MB = (long)Bn * LB;

    char* w = (char*)d_ws;
    size_t off = 0;
    auto alc = [&](size_t bytes) { void* p = w + off; off += (bytes + 255) & ~(size_t)255; return p; };

    ushort* WaT  = (ushort*)alc((size_t)DH * DA * 2);
    ushort* WbT  = (ushort*)alc((size_t)DH * DB * 2);
    ushort* WcoT = (ushort*)alc((size_t)DH * DH * 2);
    ushort* WoaT = (ushort*)alc((size_t)DA * DH * 2);
    ushort* WobT = (ushort*)alc((size_t)DB * DH * 2);
    ushort* h_a  = (ushort*)alc((size_t)MA * DH * 2);
    ushort* h_b  = (ushort*)alc((size_t)MB * DH * 2);
    ushort* h_aT = (ushort*)alc((size_t)Bn * DH * LA * 2);
    ushort* h_bT = (ushort*)alc((size_t)Bn * DH * LB * 2);
    ushort* Ma   = (ushort*)alc((size_t)MA * DH * 2);
    ushort* E    = (ushort*)alc((size_t)Bn * LA * LB * 2);
    ushort* ET   = (ushort*)alc((size_t)Bn * LB * LA * 2);
    ushort* Pa   = (ushort*)alc((size_t)MA * DH * 2);
    ushort* Pb   = (ushort*)alc((size_t)MB * DH * 2);
    float*  rsum = (float*)alc((size_t)Bn * LA * 4);
    float*  csum = (float*)alc((size_t)Bn * LB * 4);

    // bf16 copies of z_a, z_b aliased into E's region (dead before E is written)
    ushort* za16 = E;
    ushort* zb16 = E + (size_t)MA * DA;

    dim3 blk(512, 1, 1);
    dim3 blk256(256, 1, 1);
    dim3 tb(32, 8, 1);
    const int SHM = 2 * BUF_U * 2;   // 131072 B dynamic LDS

    // weight transposes (f32 -> bf16, [K][N] -> [N][K])
    tcast<<<dim3(DH / 32, DA / 32, 1), tb, 0, stream>>>(Wa,  WaT,  DA, DH);
    tcast<<<dim3(DH / 32, DB / 32, 1), tb, 0, stream>>>(Wb,  WbT,  DB, DH);
    tcast<<<dim3(DH / 32, DH / 32, 1), tb, 0, stream>>>(Wco, WcoT, DH, DH);
    tcast<<<dim3(DA / 32, DH / 32, 1), tb, 0, stream>>>(Woa, WoaT, DH, DA);
    tcast<<<dim3(DB / 32, DH / 32, 1), tb, 0, stream>>>(Wob, WobT, DH, DB);

    // activations f32 -> bf16
    cast32to16<<<dim3(2048, 1, 1), blk256, 0, stream>>>(z_a, za16, MA * DA);
    cast32to16<<<dim3(2048, 1, 1), blk256, 0, stream>>>(z_b, zb16, MB * DB);

    // zero softmax denominators (rsum & csum are contiguous)
    hipMemsetAsync(rsum, 0, (size_t)Bn * (LA + LB) * sizeof(float), stream);

    // h_a = z_a @ Wa + ba   (also writes h_aT per batch)
    gemm_bt<0, true, true><<<dim3(MA / BM, DH / BN, 1), blk, SHM, stream>>>(
        za16, WaT, h_a, h_aT, ba, nullptr, nullptr, nullptr, nullptr,
        (int)MA, DH, DA, DA, DA, DH, 0, 0, 0, (long)DH * LA, 0, LA, 11);

    // h_b = z_b @ Wb + bb   (also writes h_bT per batch)
    gemm_bt<0, true, true><<<dim3(MB / BM, DH / BN, 1), blk, SHM, stream>>>(
        zb16, WbT, h_b, h_bT, bb, nullptr, nullptr, nullptr, nullptr,
        (int)MB, DH, DB, DB, DB, DH, 0, 0, 0, (long)DH * LB, 0, LB, 11);

    // Ma = h_a @ W_co
    gemm_bt<0, false, false><<<dim3(MA / BM, DH / BN, 1), blk, SHM, stream>>>(
        h_a, WcoT, Ma, nullptr, nullptr, nullptr, nullptr, nullptr, nullptr,
        (int)MA, DH, DH, DH, DH, DH, 0, 0, 0, 0, 0, 0, 0);

    // scores: E = exp(tanh(Ma @ h_b^T)), E^T, rowsum, colsum  (batched)
    gemm_bt<1, false, false><<<dim3(LA / BM, LB / BN, Bn), blk, SHM, stream>>>(
        Ma, h_b, E, ET, nullptr, nullptr, rsum, csum, nullptr,
        LA, LB, DH, DH, DH, LB,
        (long)LA * DH, (long)LB * DH, (long)LA * LB, (long)LB * LA, LA, LA, 0);

    // Pa = (E @ h_b) / rowsum  (batched)
    gemm_bt<2, false, false><<<dim3(LA / BM, DH / BN, Bn), blk, SHM, stream>>>(
        E, h_bT, Pa, nullptr, nullptr, nullptr, nullptr, nullptr, rsum,
        LA, DH, LB, LB, LB, DH,
        (long)LA * LB, (long)DH * LB, (long)LA * DH, 0, LA, 0, 0);

    // Pb = (E^T @ h_a) / colsum  (batched)
    gemm_bt<2, false, false><<<dim3(LB / BM, DH / BN, Bn), blk, SHM, stream>>>(
        ET, h_aT, Pb, nullptr, nullptr, nullptr, nullptr, nullptr, csum,
        LB, DH, LA, LA, LA, DH,
        (long)LB * LA, (long)DH * LA, (long)LB * DH, 0, LB, 0, 0);

    float* outA = (float*)d_out;
    float* outB = outA + MA * DA;

    // z_a_pre = Pa @ Woa + boa + z_a  -> d_out (f32, in place for LN)
    gemm_bt<3, true, false><<<dim3(MA / BM, DA / BN, 1), blk, SHM, stream>>>(
        Pa, WoaT, outA, nullptr, boa, z_a, nullptr, nullptr, nullptr,
        (int)MA, DA, DH, DH, DH, DA, 0, 0, 0, 0, 0, 0, 0);

    // z_b_pre = Pb @ Wob + bob + z_b  -> d_out
    gemm_bt<3, true, false><<<dim3(MB / BM, DB / BN, 1), blk, SHM, stream>>>(
        Pb, WobT, outB, nullptr, bob, z_b, nullptr, nullptr, nullptr,
        (int)MB, DB, DH, DH, DH, DB, 0, 0, 0, 0, 0, 0, 0);

    // LayerNorms in place on d_out
    ln_rows<768><<<dim3((unsigned)MA, 1, 1), blk256, 0, stream>>>(outA, ga, beta_a);
    ln_rows<512><<<dim3((unsigned)MB, 1, 1), blk256, 0, stream>>>(outB, gb, beta_b);
}

// Round 8
// 704.553 us; speedup vs baseline: 1.0312x; 1.0131x over previous
//
#include <hip/hip_runtime.h>
#include <stdint.h>

typedef short bf16x8 __attribute__((ext_vector_type(8)));
typedef float f32x16 __attribute__((ext_vector_type(16)));

#define BM 256
#define BN 256
#define BK 64
#define ABUF_U 16384   // 256*64 ushorts (32KB) A region
#define BUF_U  32768   // A+B per buffer in ushorts (64KB); 2 buffers = 128KB

#define AS1 __attribute__((address_space(1)))
#define AS3 __attribute__((address_space(3)))

__device__ __forceinline__ ushort f2bf(float x) {
    uint32_t u = __float_as_uint(x);
    u += 0x7FFFu + ((u >> 16) & 1u);
    return (ushort)(u >> 16);
}

__device__ __forceinline__ void gload16(const void* g, void* l) {
    __builtin_amdgcn_global_load_lds((const AS1 void*)g, (AS3 void*)l, 16, 0, 0);
}

// issue 2 staging loads (chunks i0, i0+1 of 8) for K-offset kt into buffer buf
#define ISSUE2(kt, buf, i0)                                                          \
    do {                                                                             \
        gload16(((i0) < 4 ? Ap : Bp) + goff[i0] + (kt), smem + (buf)*BUF_U + loff[i0]); \
        gload16((((i0)+1) < 4 ? Ap : Bp) + goff[(i0)+1] + (kt), smem + (buf)*BUF_U + loff[(i0)+1]); \
    } while (0)

// C[M,N] = A[M,K] * B[N,K]^T, bf16 MFMA 32x32x16.
// 256x256 tile, 512 threads (8 waves: 2M x 4N, per-wave 128x64 = 4x2 32x32 tiles).
// K-loop: 2 barriers/tile; tile interior (24 ds_read_b128 + 32 MFMA + 6 prefetch
// gloads) is left to the compiler's own lgkmcnt-counted software pipelining so
// ds_read latency/conflicts overlap MFMA. Counted vmcnt(2) per tile (T4).
// 32x32 C/D layout (col=lane&31, row=(reg&3)+8*(reg>>2)+4*(lane>>5)) makes every
// row-major store instruction cover full 64B lines -> no partial-line RMW.
// Grid: bijective XCD swizzle (T1/m204) for per-XCD L2 panel reuse.
template<int MODE, bool HAS_BIAS, bool WRITE_T>
__global__ __launch_bounds__(512, 2)
void gemm_bt(const ushort* __restrict__ Aptr_, const ushort* __restrict__ Bptr_,
             void* __restrict__ Cptr_, ushort* __restrict__ CTptr_,
             const float* __restrict__ bias, const float* __restrict__ resid_,
             float* __restrict__ rsum_, float* __restrict__ csum_,
             const float* __restrict__ scale_,
             int M, int N, int K, int lda, int ldb, int ldc,
             long sA, long sB, long sC, long sCT, long sSum,
             int ldct, int rbshift)
{
    extern __shared__ ushort smem[];   // 2 * BUF_U ushorts (128KB)

    // ---- bijective XCD swizzle (T1, m204) ----
    const int gx = gridDim.x, gy = gridDim.y;
    const int nwg = gx * gy * (int)gridDim.z;
    int flat = ((int)blockIdx.z * gy + (int)blockIdx.y) * gx + (int)blockIdx.x;
    {
        const int q8 = nwg >> 3, r8 = nwg & 7;
        const int xcd = flat & 7, loc = flat >> 3;
        flat = (xcd < r8 ? xcd * (q8 + 1) : r8 * (q8 + 1) + (xcd - r8) * q8) + loc;
    }
    const int z   = flat / (gx * gy);
    const int rem = flat - z * (gx * gy);
    const int m0  = (rem % gx) * BM;
    const int n0  = (rem / gx) * BN;

    const int tid  = threadIdx.x;
    const int lane = tid & 63;
    const int wave = tid >> 6;
    const int wr   = wave >> 2;        // 0..1 -> rows wr*128..+128
    const int wcn  = wave & 3;         // 0..3 -> cols wcn*64..+64
    const int lr   = lane & 31, lh = lane >> 5;

    const ushort* Ap = Aptr_ + z * sA;
    const ushort* Bp = Bptr_ + z * sB;

    // staging: linear LDS dest, XOR-swizzled global source chunk (both-sides).
    long goff[8]; int loff[8];
    #pragma unroll
    for (int u = 0; u < 4; ++u) {
        const int li  = u * 512 + tid;       // chunk 0..2047 (A and B each)
        const int row = li >> 3;             // 0..255
        const int gck = (li & 7) ^ (row & 7);
        goff[u]     = (long)(m0 + row) * lda + gck * 8;
        loff[u]     = li * 8;
        goff[u + 4] = (long)(n0 + row) * ldb + gck * 8;
        loff[u + 4] = ABUF_U + li * 8;
    }

    f32x16 acc[4][2] = {};

    const int nk = K / BK;
    // prologue: stage tile 0 into buf 0 (8 loads/thread)
    ISSUE2(0, 0, 0); ISSUE2(0, 0, 2); ISSUE2(0, 0, 4); ISSUE2(0, 0, 6);

    for (int t = 0; t < nk; ++t) {
        const int cur = t & 1, nxt = cur ^ 1;
        const ushort* As = smem + cur * BUF_U;
        const ushort* Bs = As + ABUF_U;
        const bool pf = (t + 1 < nk);
        const int kt1 = (t + 1) * BK;

        if (pf) {
            ISSUE2(kt1, nxt, 0);
            asm volatile("s_waitcnt vmcnt(2)" ::: "memory");  // tile t landed; 2 prefetch in flight
        } else {
            asm volatile("s_waitcnt vmcnt(0)" ::: "memory");  // tail drain
        }
        __builtin_amdgcn_s_barrier();

        // tile interior: no manual fences — compiler pipelines ds_read vs MFMA
        #pragma unroll
        for (int kk = 0; kk < 4; ++kk) {          // 4 k-steps of 16
            bf16x8 af[4], bfv[2];
            #pragma unroll
            for (int tm = 0; tm < 4; ++tm) {
                const int row = wr * 128 + tm * 32 + lr;
                const int ck  = (kk * 2 + lh) ^ (row & 7);
                af[tm] = *(const bf16x8*)&As[row * BK + ck * 8];
            }
            #pragma unroll
            for (int tn = 0; tn < 2; ++tn) {
                const int row = wcn * 64 + tn * 32 + lr;
                const int ck  = (kk * 2 + lh) ^ (row & 7);
                bfv[tn] = *(const bf16x8*)&Bs[row * BK + ck * 8];
            }
            if (pf) {
                if (kk == 0)      ISSUE2(kt1, nxt, 2);
                else if (kk == 1) ISSUE2(kt1, nxt, 4);
                else if (kk == 2) ISSUE2(kt1, nxt, 6);
            }
            #pragma unroll
            for (int tm = 0; tm < 4; ++tm)
                #pragma unroll
                for (int tn = 0; tn < 2; ++tn)
                    acc[tm][tn] = __builtin_amdgcn_mfma_f32_32x32x16_bf16(
                        af[tm], bfv[tn], acc[tm][tn], 0, 0, 0);
        }

        asm volatile("s_waitcnt lgkmcnt(0)" ::: "memory");  // my reads of cur done
        __builtin_amdgcn_s_barrier();                        // all waves done -> cur reusable
    }

    // ---- epilogues (direct stores; 32x32 layout -> full-line coalescing) ----
    const int colb0 = n0 + wcn * 64 + lr;         // tn=0 col
    const int rowbw = m0 + wr * 128 + 4 * lh;     // + tm*32 + (rr&3) + 8*(rr>>2)

    if constexpr (MODE == 3) {
        float* Co = (float*)Cptr_;
        #pragma unroll
        for (int tm = 0; tm < 4; ++tm)
            #pragma unroll
            for (int tn = 0; tn < 2; ++tn) {
                const int col = colb0 + tn * 32;
                const float bv = bias[col];
                #pragma unroll
                for (int q = 0; q < 4; ++q)
                    #pragma unroll
                    for (int s = 0; s < 4; ++s) {
                        const int row = rowbw + tm * 32 + q * 8 + s;
                        const long idx = (long)row * ldc + col;
                        Co[idx] = acc[tm][tn][q * 4 + s] + bv + resid_[idx];
                    }
            }
    } else if constexpr (MODE == 0) {
        ushort* Cp = (ushort*)Cptr_ + z * sC;
        #pragma unroll
        for (int tm = 0; tm < 4; ++tm)
            #pragma unroll
            for (int tn = 0; tn < 2; ++tn) {
                const int col = colb0 + tn * 32;
                const float bv = HAS_BIAS ? bias[col] : 0.f;
                ushort us[16];
                #pragma unroll
                for (int rr = 0; rr < 16; ++rr) us[rr] = f2bf(acc[tm][tn][rr] + bv);
                #pragma unroll
                for (int q = 0; q < 4; ++q)
                    #pragma unroll
                    for (int s = 0; s < 4; ++s)
                        Cp[(long)(rowbw + tm * 32 + q * 8 + s) * ldc + col] = us[q * 4 + s];
                if constexpr (WRITE_T) {
                    #pragma unroll
                    for (int q = 0; q < 4; ++q) {
                        const int gr = rowbw + tm * 32 + q * 8;
                        const int bb = gr >> rbshift;
                        const int ii = gr & ((1 << rbshift) - 1);
                        *(ushort4*)&CTptr_[(long)bb * sCT + (long)col * ldct + ii] =
                            make_ushort4(us[q * 4 + 0], us[q * 4 + 1], us[q * 4 + 2], us[q * 4 + 3]);
                    }
                }
            }
    } else if constexpr (MODE == 1) {
        ushort* Ep  = (ushort*)Cptr_ + z * sC;
        ushort* ETp = CTptr_ + z * sCT;
        float* rs = rsum_ + z * sSum;
        float* cs = csum_ + z * sSum;
        float colp[2] = {0.f, 0.f};
        #pragma unroll
        for (int tm = 0; tm < 4; ++tm) {
            float rowp[16];
            #pragma unroll
            for (int rr = 0; rr < 16; ++rr) rowp[rr] = 0.f;
            #pragma unroll
            for (int tn = 0; tn < 2; ++tn) {
                const int col = colb0 + tn * 32;
                ushort us[16];
                #pragma unroll
                for (int rr = 0; rr < 16; ++rr) {
                    const float x  = acc[tm][tn][rr];
                    const float th = 1.f - 2.f / (__expf(2.f * x) + 1.f);  // tanh(x)
                    const float e  = __expf(th);
                    rowp[rr] += e;
                    colp[tn] += e;
                    us[rr] = f2bf(e);
                }
                #pragma unroll
                for (int q = 0; q < 4; ++q) {
                    #pragma unroll
                    for (int s = 0; s < 4; ++s)
                        Ep[(long)(rowbw + tm * 32 + q * 8 + s) * ldc + col] = us[q * 4 + s];
                    const int gr = rowbw + tm * 32 + q * 8;
                    *(ushort4*)&ETp[(long)col * ldct + gr] =
                        make_ushort4(us[q * 4 + 0], us[q * 4 + 1], us[q * 4 + 2], us[q * 4 + 3]);
                }
            }
            #pragma unroll
            for (int rr = 0; rr < 16; ++rr) {
                float v = rowp[rr];
                v += __shfl_xor(v, 1);  v += __shfl_xor(v, 2);
                v += __shfl_xor(v, 4);  v += __shfl_xor(v, 8);
                v += __shfl_xor(v, 16);
                if (lr == 0)
                    atomicAdd(&rs[rowbw + tm * 32 + (rr & 3) + 8 * (rr >> 2)], v);
            }
        }
        #pragma unroll
        for (int tn = 0; tn < 2; ++tn) {
            float v = colp[tn];
            v += __shfl_xor(v, 32);
            if (lh == 0) atomicAdd(&cs[colb0 + tn * 32], v);
        }
    } else { // MODE == 2
        const float* sc = scale_ + z * sSum;
        ushort* Cp = (ushort*)Cptr_ + z * sC;
        #pragma unroll
        for (int tm = 0; tm < 4; ++tm) {
            float rcp[16];
            #pragma unroll
            for (int rr = 0; rr < 16; ++rr)
                rcp[rr] = 1.f / sc[rowbw + tm * 32 + (rr & 3) + 8 * (rr >> 2)];
            #pragma unroll
            for (int tn = 0; tn < 2; ++tn) {
                const int col = colb0 + tn * 32;
                #pragma unroll
                for (int q = 0; q < 4; ++q)
                    #pragma unroll
                    for (int s = 0; s < 4; ++s)
                        Cp[(long)(rowbw + tm * 32 + q * 8 + s) * ldc + col] =
                            f2bf(acc[tm][tn][q * 4 + s] * rcp[q * 4 + s]);
            }
        }
    }
}

// f32 -> bf16 elementwise (vectorized 8/thread, grid-stride)
__global__ __launch_bounds__(256)
void cast32to16(const float* __restrict__ in, ushort* __restrict__ out, long n) {
    const long stride = (long)gridDim.x * 256 * 8;
    for (long i = ((long)blockIdx.x * 256 + threadIdx.x) * 8; i < n; i += stride) {
        const float4 f0 = *(const float4*)(in + i);
        const float4 f1 = *(const float4*)(in + i + 4);
        uint4 w;
        w.x = (uint)f2bf(f0.x) | ((uint)f2bf(f0.y) << 16);
        w.y = (uint)f2bf(f0.z) | ((uint)f2bf(f0.w) << 16);
        w.z = (uint)f2bf(f1.x) | ((uint)f2bf(f1.y) << 16);
        w.w = (uint)f2bf(f1.z) | ((uint)f2bf(f1.w) << 16);
        *(uint4*)(out + i) = w;
    }
}

// f32 [R][C] -> bf16 [C][R]
__global__ __launch_bounds__(256)
void tcast(const float* __restrict__ in, ushort* __restrict__ out, int R, int C) {
    __shared__ float t[32][33];
    const int bx = blockIdx.x * 32, by = blockIdx.y * 32;
    const int tx = threadIdx.x, ty = threadIdx.y; // (32, 8)
    for (int i = ty; i < 32; i += 8) {
        const int r = by + i, cc = bx + tx;
        if (r < R && cc < C) t[i][tx] = in[(long)r * C + cc];
    }
    __syncthreads();
    for (int i = ty; i < 32; i += 8) {
        const int cc = bx + i, r = by + tx;
        if (cc < C && r < R) out[(long)cc * R + r] = f2bf(t[tx][i]);
    }
}

// in-place LayerNorm, one row per block
template<int D>
__global__ __launch_bounds__(256)
void ln_rows(float* __restrict__ y, const float* __restrict__ gam, const float* __restrict__ bet) {
    constexpr int NV = D / 256;
    const long row = blockIdx.x;
    float* p = y + row * D;
    const int tid = threadIdx.x;
    float v[NV];
    float s = 0.f, s2 = 0.f;
    #pragma unroll
    for (int k = 0; k < NV; ++k) {
        v[k] = p[tid + k * 256];
        s += v[k]; s2 += v[k] * v[k];
    }
    #pragma unroll
    for (int off = 1; off < 64; off <<= 1) {
        s  += __shfl_xor(s, off);
        s2 += __shfl_xor(s2, off);
    }
    __shared__ float ws[4], ws2[4];
    const int wave = tid >> 6, lane = tid & 63;
    if (lane == 0) { ws[wave] = s; ws2[wave] = s2; }
    __syncthreads();
    s  = ws[0] + ws[1] + ws[2] + ws[3];
    s2 = ws2[0] + ws2[1] + ws2[2] + ws2[3];
    const float mu  = s / D;
    const float var = s2 / D - mu * mu;
    const float rstd = rsqrtf(var + 1e-5f);
    #pragma unroll
    for (int k = 0; k < NV; ++k) {
        const int i = tid + k * 256;
        p[i] = (v[k] - mu) * rstd * gam[i] + bet[i];
    }
}

extern "C" void kernel_launch(void* const* d_in, const int* in_sizes, int n_in,
                              void* d_out, int out_size, void* d_ws, size_t ws_size,
                              hipStream_t stream)
{
    (void)in_sizes; (void)n_in; (void)out_size; (void)ws_size;
    const float* z_a    = (const float*)d_in[0];
    const float* z_b    = (const float*)d_in[1];
    const float* Wa     = (const float*)d_in[2];
    const float* ba     = (const float*)d_in[3];
    const float* Wb     = (const float*)d_in[4];
    const float* bb     = (const float*)d_in[5];
    const float* Wco    = (const float*)d_in[6];
    const float* Woa    = (const float*)d_in[7];
    const float* boa    = (const float*)d_in[8];
    const float* Wob    = (const float*)d_in[9];
    const float* bob    = (const float*)d_in[10];
    const float* ga     = (const float*)d_in[11];
    const float* beta_a = (const float*)d_in[12];
    const float* gb     = (const float*)d_in[13];
    const float* beta_b = (const float*)d_in[14];

    const int Bn = 16, LA = 2048, LB = 2048, DA = 768, DB = 512, DH = 512;
    const long MA = (long)Bn * LA;
    const long MB = (long)Bn * LB;

    char* w = (char*)d_ws;
    size_t off = 0;
    auto alc = [&](size_t bytes) { void* p = w + off; off += (bytes + 255) & ~(size_t)255; return p; };

    ushort* WaT  = (ushort*)alc((size_t)DH * DA * 2);
    ushort* WbT  = (ushort*)alc((size_t)DH * DB * 2);
    ushort* WcoT = (ushort*)alc((size_t)DH * DH * 2);
    ushort* WoaT = (ushort*)alc((size_t)DA * DH * 2);
    ushort* WobT = (ushort*)alc((size_t)DB * DH * 2);
    ushort* h_a  = (ushort*)alc((size_t)MA * DH * 2);
    ushort* h_b  = (ushort*)alc((size_t)MB * DH * 2);
    ushort* h_aT = (ushort*)alc((size_t)Bn * DH * LA * 2);
    ushort* h_bT = (ushort*)alc((size_t)Bn * DH * LB * 2);
    ushort* Ma   = (ushort*)alc((size_t)MA * DH * 2);
    ushort* E    = (ushort*)alc((size_t)Bn * LA * LB * 2);
    ushort* ET   = (ushort*)alc((size_t)Bn * LB * LA * 2);
    ushort* Pa   = (ushort*)alc((size_t)MA * DH * 2);
    ushort* Pb   = (ushort*)alc((size_t)MB * DH * 2);
    float*  rsum = (float*)alc((size_t)Bn * LA * 4);
    float*  csum = (float*)alc((size_t)Bn * LB * 4);

    // bf16 copies of z_a, z_b aliased into E's region (dead before E is written)
    ushort* za16 = E;
    ushort* zb16 = E + (size_t)MA * DA;

    dim3 blk(512, 1, 1);
    dim3 blk256(256, 1, 1);
    dim3 tb(32, 8, 1);
    const int SHM = 2 * BUF_U * 2;   // 131072 B dynamic LDS

    // weight transposes (f32 -> bf16, [K][N] -> [N][K])
    tcast<<<dim3(DH / 32, DA / 32, 1), tb, 0, stream>>>(Wa,  WaT,  DA, DH);
    tcast<<<dim3(DH / 32, DB / 32, 1), tb, 0, stream>>>(Wb,  WbT,  DB, DH);
    tcast<<<dim3(DH / 32, DH / 32, 1), tb, 0, stream>>>(Wco, WcoT, DH, DH);
    tcast<<<dim3(DA / 32, DH / 32, 1), tb, 0, stream>>>(Woa, WoaT, DH, DA);
    tcast<<<dim3(DB / 32, DH / 32, 1), tb, 0, stream>>>(Wob, WobT, DH, DB);

    // activations f32 -> bf16
    cast32to16<<<dim3(2048, 1, 1), blk256, 0, stream>>>(z_a, za16, MA * DA);
    cast32to16<<<dim3(2048, 1, 1), blk256, 0, stream>>>(z_b, zb16, MB * DB);

    // zero softmax denominators (rsum & csum are contiguous)
    hipMemsetAsync(rsum, 0, (size_t)Bn * (LA + LB) * sizeof(float), stream);

    // h_a = z_a @ Wa + ba   (also writes h_aT per batch)
    gemm_bt<0, true, true><<<dim3(MA / BM, DH / BN, 1), blk, SHM, stream>>>(
        za16, WaT, h_a, h_aT, ba, nullptr, nullptr, nullptr, nullptr,
        (int)MA, DH, DA, DA, DA, DH, 0, 0, 0, (long)DH * LA, 0, LA, 11);

    // h_b = z_b @ Wb + bb   (also writes h_bT per batch)
    gemm_bt<0, true, true><<<dim3(MB / BM, DH / BN, 1), blk, SHM, stream>>>(
        zb16, WbT, h_b, h_bT, bb, nullptr, nullptr, nullptr, nullptr,
        (int)MB, DH, DB, DB, DB, DH, 0, 0, 0, (long)DH * LB, 0, LB, 11);

    // Ma = h_a @ W_co
    gemm_bt<0, false, false><<<dim3(MA / BM, DH / BN, 1), blk, SHM, stream>>>(
        h_a, WcoT, Ma, nullptr, nullptr, nullptr, nullptr, nullptr, nullptr,
        (int)MA, DH, DH, DH, DH, DH, 0, 0, 0, 0, 0, 0, 0);

    // scores: E = exp(tanh(Ma @ h_b^T)), E^T, rowsum, colsum  (batched)
    gemm_bt<1, false, false><<<dim3(LA / BM, LB / BN, Bn), blk, SHM, stream>>>(
        Ma, h_b, E, ET, nullptr, nullptr, rsum, csum, nullptr,
        LA, LB, DH, DH, DH, LB,
        (long)LA * DH, (long)LB * DH, (long)LA * LB, (long)LB * LA, LA, LA, 0);

    // Pa = (E @ h_b) / rowsum  (batched)
    gemm_bt<2, false, false><<<dim3(LA / BM, DH / BN, Bn), blk, SHM, stream>>>(
        E, h_bT, Pa, nullptr, nullptr, nullptr, nullptr, nullptr, rsum,
        LA, DH, LB, LB, LB, DH,
        (long)LA * LB, (long)DH * LB, (long)LA * DH, 0, LA, 0, 0);

    // Pb = (E^T @ h_a) / colsum  (batched)
    gemm_bt<2, false, false><<<dim3(LB / BM, DH / BN, Bn), blk, SHM, stream>>>(
        ET, h_aT, Pb, nullptr, nullptr, nullptr, nullptr, nullptr, csum,
        LB, DH, LA, LA, LA, DH,
        (long)LB * LA, (long)DH * LA, (long)LB * DH, 0, LB, 0, 0);

    float* outA = (float*)d_out;
    float* outB = outA + MA * DA;

    // z_a_pre = Pa @ Woa + boa + z_a  -> d_out (f32, in place for LN)
    gemm_bt<3, true, false><<<dim3(MA / BM, DA / BN, 1), blk, SHM, stream>>>(
        Pa, WoaT, outA, nullptr, boa, z_a, nullptr, nullptr, nullptr,
        (int)MA, DA, DH, DH, DH, DA, 0, 0, 0, 0, 0, 0, 0);

    // z_b_pre = Pb @ Wob + bob + z_b  -> d_out
    gemm_bt<3, true, false><<<dim3(MB / BM, DB / BN, 1), blk, SHM, stream>>>(
        Pb, WobT, outB, nullptr, bob, z_b, nullptr, nullptr, nullptr,
        (int)MB, DB, DH, DH, DH, DB, 0, 0, 0, 0, 0, 0, 0);

    // LayerNorms in place on d_out
    ln_rows<768><<<dim3((unsigned)MA, 1, 1), blk256, 0, stream>>>(outA, ga, beta_a);
    ln_rows<512><<<dim3((unsigned)MB, 1, 1), blk256, 0, stream>>>(outB, gb, beta_b);
}